// Round 13
// baseline (79.851 us; speedup 1.0000x reference)
//
#include <hip/hip_runtime.h>
#include <hip/hip_bf16.h>
#include <stdint.h>

#define HH 128
#define WW 128
#define HWPX 16384
#define BIGL 16384           // background sentinel
#define NT 1024
#define PPT 16               // contiguous pixels per thread (one 16-col row chunk)
#define LSTRIDE 32           // loss slot stride (floats): one 128B line per block

// find with path-halving via atomicMin (monotone decrease -> acyclic, safe
// under concurrent unions; R4-validated fastest variant)
__device__ __forceinline__ int findRootH(int* L, int x) {
    int p = L[x];
    while (p != x) {
        int g = L[p];
        if (g != p) atomicMin(&L[x], g);
        x = p; p = g;
    }
    return x;
}
// post-merge find with plain-store halving (no concurrent unions)
__device__ __forceinline__ int findRootF(int* L, int x) {
    int p = L[x];
    while (p != x) {
        int g = L[p];
        if (g != p) L[x] = g;
        x = p; p = g;
    }
    return p;
}
// ECL-CC style hook: on failed atomicMin continue from returned pointer
__device__ __forceinline__ void uni(int* L, int a, int b) {
    a = findRootH(L, a);
    b = findRootH(L, b);
    while (a != b) {
        if (a > b) { int t = a; a = b; b = t; }
        int old = atomicMin(&L[b], a);
        if (old == b) break;
        b = old;
    }
}

__device__ __forceinline__ int wsumi(int v)    { for (int o = 32; o; o >>= 1) v += __shfl_xor(v, o, 64); return v; }
__device__ __forceinline__ float wsumf(float v){ for (int o = 32; o; o >>= 1) v += __shfl_xor(v, o, 64); return v; }
__device__ __forceinline__ int wmini(int v)    { for (int o = 32; o; o >>= 1) v = min(v, __shfl_xor(v, o, 64)); return v; }
__device__ __forceinline__ int wmaxi(int v)    { for (int o = 32; o; o >>= 1) v = max(v, __shfl_xor(v, o, 64)); return v; }

__global__ __launch_bounds__(NT)
void cc_kernel(const float* __restrict__ masks, float* __restrict__ lossP,
               int* __restrict__ counter, float* __restrict__ out) {
    __shared__ int L[HWPX];              // 64 KB: UF parent; roots get area<<16
    __shared__ unsigned rowbits[HH][4];  // 2 KB: fg bitmap
    __shared__ int s_r0, s_r1, s_c0, s_c1;
    __shared__ unsigned s_wk[32];        // per-wave top-2 pairs
    __shared__ int s_wi[16];             // per-wave fg counts
    __shared__ float s_wA[16];           // per-wave total sums
    __shared__ float s_wB[16];           // per-wave box sums

    const int tid = threadIdx.x;
    const int lane = tid & 63;
    const int wid = tid >> 6;
    const float* msk = masks + (size_t)blockIdx.x * HWPX;
    const int base = tid * PPT;
    const int row  = base >> 7;
    const int col0 = base & 127;

    // ---- vectorized load, fg detect, total sum, run-head labels ----
    float vals[PPT];
    const float4* m4 = (const float4*)(msk + base);
#pragma unroll
    for (int q = 0; q < 4; ++q) {
        float4 v = m4[q];
        vals[q * 4 + 0] = v.x; vals[q * 4 + 1] = v.y;
        vals[q * 4 + 2] = v.z; vals[q * 4 + 3] = v.w;
    }
    unsigned fgbits = 0;
    float tsum = 0.f;
    int lab[PPT];
    {
        int start = -1;
#pragma unroll
        for (int k = 0; k < PPT; ++k) {
            tsum += vals[k];
            if (vals[k] > 0.f) {
                fgbits |= 1u << k;
                if (start < 0) start = k;
                lab[k] = base + start;
            } else {
                start = -1;
                lab[k] = BIGL;
            }
        }
    }
    {
        int4* Lv = (int4*)(L + base);
#pragma unroll
        for (int q = 0; q < 4; ++q)
            Lv[q] = make_int4(lab[q * 4], lab[q * 4 + 1], lab[q * 4 + 2], lab[q * 4 + 3]);
    }
    unsigned lf = __shfl(fgbits, lane > 0 ? lane - 1 : lane, 64);
    unsigned rf = __shfl(fgbits, lane < 63 ? lane + 1 : lane, 64);
    const unsigned leftbit  = (col0 > 0)   ? ((lf >> 15) & 1u) : 0u;
    const unsigned rightbit = (col0 < 112) ? (rf & 1u)         : 0u;
    unsigned other = __shfl_xor(fgbits, 1, 64);
    if (!(tid & 1)) rowbits[row][(tid >> 1) & 3] = fgbits | (other << 16);

    tsum = wsumf(tsum);
    int fgc = wsumi(__popc(fgbits));
    if (lane == 0) { s_wA[wid] = tsum; s_wi[wid] = fgc; }
    if (tid == 0) { s_r0 = HH; s_r1 = -1; s_c0 = WW; s_c1 = -1; }
    __syncthreads();                                   // B1

    // ---- merge pass (event-masked dedup'd unions; R11 core) ----
    if (fgbits) {
        unsigned up = 0;
        if (row > 0) {
            const int wi  = col0 >> 5;
            const int off = col0 & 31;
            unsigned w0 = rowbits[row - 1][wi];
            unsigned w1 = (wi < 3) ? rowbits[row - 1][wi + 1] : 0u;
            unsigned long long uv = ((unsigned long long)w1 << 32) | w0;
            if (off == 16) {
                up = (unsigned)(uv >> 15) & 0x3FFFFu;
            } else {
                unsigned lw = (col0 > 0) ? rowbits[row - 1][wi - 1] : 0u;
                up = (unsigned)((uv << 1) | (lw >> 31)) & 0x3FFFFu;
            }
        }
        if ((fgbits & 1u) && leftbit) uni(L, base, base - 1);
        const unsigned ULv = up & 0xFFFFu;
        const unsigned UPv = (up >> 1) & 0xFFFFu;
        const unsigned URv = (up >> 2) & 0xFFFFu;
        const unsigned lFv = ((fgbits << 1) | leftbit) & 0xFFFFu;
        const unsigned rFv = (fgbits >> 1) | (rightbit << 15);
        unsigned m = fgbits & ( (~lFv & (ULv | UPv | URv))
                              | (lFv & ((UPv & ~ULv) | (~rFv & URv & ~UPv))) );
        while (m) {
            int k = __ffs(m) - 1; m &= m - 1;
            unsigned t = ~fgbits & ((1u << k) - 1u);
            int head = base + (t ? (32 - __builtin_clz(t)) : 0);
            unsigned UL = (ULv >> k) & 1u;
            unsigned UP = (UPv >> k) & 1u;
            unsigned UR = (URv >> k) & 1u;
            unsigned lF = (lFv >> k) & 1u;
            unsigned rF = (rFv >> k) & 1u;
            int i = base + k;
            if (!lF) {
                if (UL)        uni(L, head, i - WW - 1);
                if (UP && !UL) uni(L, head, i - WW);
                if (UR && !UP) uni(L, head, i - WW + 1);
            } else {
                if (UP && !UL)        uni(L, head, i - WW);
                if (!rF && UR && !UP) uni(L, head, i - WW + 1);
            }
        }
    }
    __syncthreads();                                   // B2

    // ---- flatten: one find per run; compress run heads ----
    int rr[PPT];
    int firstRoot = 0x7FFFFFFF;
    {
        int cur = -1;
#pragma unroll
        for (int k = 0; k < PPT; ++k) {
            rr[k] = -1;
            if (fgbits & (1u << k)) {
                if (k == 0 || !(fgbits & (1u << (k - 1)))) {
                    cur = findRootF(L, base + k);
                    L[base + k] = cur;
                }
                rr[k] = cur;
                if (firstRoot == 0x7FFFFFFF) firstRoot = cur;
            }
        }
    }
    __syncthreads();                                   // B3

    // ---- areas: wave-combined dominant root + run-length atomics ----
    {
        const int R0 = wmini(firstRoot);
        int giant = 0, prev = -1, cnt = 0;
#pragma unroll
        for (int k = 0; k < PPT; ++k) {
            if (!(fgbits & (1u << k))) continue;
            int r = rr[k];
            if (r == R0) ++giant;
            else if (r == prev) ++cnt;
            else {
                if (cnt) atomicAdd(&L[prev], cnt << 16);
                prev = r; cnt = 1;
            }
        }
        if (cnt) atomicAdd(&L[prev], cnt << 16);
        int g = wsumi(giant);
        if (lane == 0 && R0 != 0x7FFFFFFF && g) atomicAdd(&L[R0], g << 16);
    }
    __syncthreads();                                   // B4

    // ---- top-2 scan over run heads (fg roots only) ----
    unsigned b1 = 0, b2 = 0;
    {
        unsigned m = fgbits & ~(fgbits << 1);          // chunk-local run heads
        while (m) {
            int k = __ffs(m) - 1; m &= m - 1;
            int h = base + k;
            int e = L[h];
            if ((e & 0xFFFF) == h && (e >> 16) != 0) {
                unsigned key = ((unsigned)(e >> 16) << 15) | (unsigned)(BIGL - h);
                if (key > b1) { b2 = b1; b1 = key; }
                else if (key > b2) b2 = key;
            }
        }
    }
    for (int o = 32; o; o >>= 1) {
        unsigned p1 = __shfl_xor(b1, o, 64);
        unsigned p2 = __shfl_xor(b2, o, 64);
        if (p1 > b1) { b2 = (b1 > p2 ? b1 : p2); b1 = p1; }
        else if (p1 > b2) b2 = p1;
    }
    if (lane == 0) { s_wk[wid * 2] = b1; s_wk[wid * 2 + 1] = b2; }
    __syncthreads();                                   // B5

    // ---- every thread: global top-2 (incl. background) from s_wk/s_wi ----
    unsigned g1 = 0, g2 = 0;
    {
        int fgtot = 0;
#pragma unroll
        for (int w = 0; w < 16; ++w) fgtot += s_wi[w];
        int bg = HWPX - fgtot;
        if (bg > 0) g1 = (unsigned)bg << 15;           // bg key (label BIGL -> suffix 0)
#pragma unroll
        for (int w = 0; w < 16; ++w) {
            unsigned o1 = s_wk[w * 2], o2 = s_wk[w * 2 + 1];
            if (o1 > g1) { g2 = (g1 > o2 ? g1 : o2); g1 = o1; }
            else if (o1 > g2) g2 = o1;
        }
    }
    const unsigned k2 = g2;
    const bool have2 = (k2 >> 15) != 0;
    const int j = BIGL - (int)(k2 & 0x7FFFu);          // runner-up (BIGL == bg)

    // ---- bbox of component j (wave-combined atomics) ----
    if (have2) {
        int lc0 = WW, lc1 = -1;
#pragma unroll
        for (int k = 0; k < PPT; ++k) {
            bool inc = (fgbits & (1u << k)) ? (rr[k] == j) : (j == BIGL);
            if (inc) {
                int c = col0 + k;
                lc0 = min(lc0, c); lc1 = max(lc1, c);
            }
        }
        int lr0 = (lc1 >= 0) ? row : HH;
        int lr1 = (lc1 >= 0) ? row : -1;
        lr0 = wmini(lr0); lr1 = wmaxi(lr1);
        lc0 = wmini(lc0); lc1 = wmaxi(lc1);
        if (lane == 0 && lr1 >= 0) {
            atomicMin(&s_r0, lr0); atomicMax(&s_r1, lr1);
            atomicMin(&s_c0, lc0); atomicMax(&s_c1, lc1);
        }
    }
    __syncthreads();                                   // B6

    // ---- sum inside box (from registers) ----
    float bsum = 0.f;
    if (have2) {
        int r0 = s_r0, r1 = s_r1, c0 = s_c0, c1 = s_c1;
        if (row >= r0 && row <= r1) {
#pragma unroll
            for (int k = 0; k < PPT; ++k) {
                int c = col0 + k;
                if (c >= c0 && c <= c1) bsum += vals[k];
            }
        }
    }
    bsum = wsumf(bsum);
    if (lane == 0) s_wB[wid] = bsum;
    __syncthreads();                                   // B7

    // ---- per-block loss + fused device-wide mean (counter tail) ----
    if (tid == 0) {
        float tot = 0.f, bx = 0.f;
#pragma unroll
        for (int w = 0; w < 16; ++w) { tot += s_wA[w]; bx += s_wB[w]; }
        lossP[(size_t)blockIdx.x * LSTRIDE] = (tot - bx) * (1.0f / 16384.0f);
        __threadfence();                               // device-scope release
        int old = atomicAdd(counter, 1);               // device-scope RMW
        if (old == (int)gridDim.x - 1) {               // last block reduces
            __threadfence();                           // acquire side
            float s = 0.f;
            const volatile float* lp = (const volatile float*)lossP;
            for (int i = 0; i < (int)gridDim.x; ++i) s += lp[(size_t)i * LSTRIDE];
            out[0] = s / (float)gridDim.x;             // fixed order: deterministic
        }
    }
}

// fallback reduction (only if workspace were implausibly small)
__global__ void reduce_kernel(const float* __restrict__ losses, float* __restrict__ out, int n) {
    __shared__ float s[4];
    int t = threadIdx.x;                      // 256 threads
    float v = 0.f;
    for (int i = t; i < n; i += 256) v += losses[i * LSTRIDE];
    for (int off = 32; off; off >>= 1) v += __shfl_down(v, off, 64);
    if ((t & 63) == 0) s[t >> 6] = v;
    __syncthreads();
    if (t == 0) out[0] = (s[0] + s[1] + s[2] + s[3]) / (float)n;
}

extern "C" void kernel_launch(void* const* d_in, const int* in_sizes, int n_in,
                              void* d_out, int out_size, void* d_ws, size_t ws_size,
                              hipStream_t stream) {
    const float* masks = (const float*)d_in[0];
    float* out = (float*)d_out;
    int nmask = in_sizes[0] / HWPX;                    // 128
    float* lossP = (float*)d_ws;                       // nmask padded loss slots
    size_t lossB = (size_t)nmask * LSTRIDE * sizeof(float);
    int* counter = (int*)((char*)d_ws + lossB);
    size_t need = lossB + sizeof(int);
    if (ws_size >= need) {
        hipMemsetAsync(counter, 0, sizeof(int), stream);
        cc_kernel<<<nmask, NT, 0, stream>>>(masks, lossP, counter, out);
    } else {
        // degenerate fallback (never expected): no counter space -> two-phase
        cc_kernel<<<nmask, NT, 0, stream>>>(masks, lossP, (int*)d_ws, out);
        reduce_kernel<<<1, 256, 0, stream>>>(lossP, out, nmask);
    }
}

// Round 14
// 47.591 us; speedup vs baseline: 1.6779x; 1.6779x over previous
//
#include <hip/hip_runtime.h>
#include <hip/hip_bf16.h>
#include <stdint.h>

#define HH 128
#define WW 128
#define HWPX 16384
#define BIGL 16384           // background sentinel
#define NT 1024
#define PPT 16               // contiguous pixels per thread (one 16-col row chunk)

// find with path-halving via atomicMin (monotone decrease -> acyclic, safe
// under concurrent unions; R4-validated fastest variant)
__device__ __forceinline__ int findRootH(int* L, int x) {
    int p = L[x];
    while (p != x) {
        int g = L[p];
        if (g != p) atomicMin(&L[x], g);
        x = p; p = g;
    }
    return x;
}
// masked find with plain-store halving: walks low-16 parent bits so it is
// robust to concurrent area atomicAdds landing in high bits of root entries.
// Halving stores only masked parent values and only to non-roots.
__device__ __forceinline__ int findRootM(int* L, int x) {
    int p = L[x] & 0xFFFF;
    while (p != x) {
        int g = L[p] & 0xFFFF;
        if (g != p) L[x] = g;
        x = p; p = g;
    }
    return p;
}
// ECL-CC style hook: on failed atomicMin continue from returned pointer
__device__ __forceinline__ void uni(int* L, int a, int b) {
    a = findRootH(L, a);
    b = findRootH(L, b);
    while (a != b) {
        if (a > b) { int t = a; a = b; b = t; }
        int old = atomicMin(&L[b], a);
        if (old == b) break;
        b = old;
    }
}

__device__ __forceinline__ int wsumi(int v)    { for (int o = 32; o; o >>= 1) v += __shfl_xor(v, o, 64); return v; }
__device__ __forceinline__ float wsumf(float v){ for (int o = 32; o; o >>= 1) v += __shfl_xor(v, o, 64); return v; }
__device__ __forceinline__ int wmini(int v)    { for (int o = 32; o; o >>= 1) v = min(v, __shfl_xor(v, o, 64)); return v; }
__device__ __forceinline__ int wmaxi(int v)    { for (int o = 32; o; o >>= 1) v = max(v, __shfl_xor(v, o, 64)); return v; }

__global__ __launch_bounds__(NT)
void cc_kernel(const float* __restrict__ masks, float* __restrict__ losses) {
    __shared__ int L[HWPX];              // 64 KB: UF parent; roots get area<<16
    __shared__ unsigned rowbits[HH][4];  // 2 KB: fg bitmap
    __shared__ int s_r0, s_r1, s_c0, s_c1;
    __shared__ unsigned s_wk[32];        // per-wave top-2 pairs
    __shared__ int s_wi[16];             // per-wave fg counts
    __shared__ float s_wA[16];           // per-wave total sums
    __shared__ float s_wB[16];           // per-wave box sums

    const int tid = threadIdx.x;
    const int lane = tid & 63;
    const int wid = tid >> 6;
    const float* msk = masks + (size_t)blockIdx.x * HWPX;
    const int base = tid * PPT;
    const int row  = base >> 7;
    const int col0 = base & 127;

    // ---- vectorized load, fg detect, total sum, run-head labels ----
    float vals[PPT];
    const float4* m4 = (const float4*)(msk + base);
#pragma unroll
    for (int q = 0; q < 4; ++q) {
        float4 v = m4[q];
        vals[q * 4 + 0] = v.x; vals[q * 4 + 1] = v.y;
        vals[q * 4 + 2] = v.z; vals[q * 4 + 3] = v.w;
    }
    unsigned fgbits = 0;
    float tsum = 0.f;
    int lab[PPT];
    {
        int start = -1;
#pragma unroll
        for (int k = 0; k < PPT; ++k) {
            tsum += vals[k];
            if (vals[k] > 0.f) {
                fgbits |= 1u << k;
                if (start < 0) start = k;
                lab[k] = base + start;
            } else {
                start = -1;
                lab[k] = BIGL;
            }
        }
    }
    {
        int4* Lv = (int4*)(L + base);
#pragma unroll
        for (int q = 0; q < 4; ++q)
            Lv[q] = make_int4(lab[q * 4], lab[q * 4 + 1], lab[q * 4 + 2], lab[q * 4 + 3]);
    }
    unsigned lf = __shfl(fgbits, lane > 0 ? lane - 1 : lane, 64);
    unsigned rf = __shfl(fgbits, lane < 63 ? lane + 1 : lane, 64);
    const unsigned leftbit  = (col0 > 0)   ? ((lf >> 15) & 1u) : 0u;
    const unsigned rightbit = (col0 < 112) ? (rf & 1u)         : 0u;
    unsigned other = __shfl_xor(fgbits, 1, 64);
    if (!(tid & 1)) rowbits[row][(tid >> 1) & 3] = fgbits | (other << 16);

    tsum = wsumf(tsum);
    int fgc = wsumi(__popc(fgbits));
    if (lane == 0) { s_wA[wid] = tsum; s_wi[wid] = fgc; }
    if (tid == 0) { s_r0 = HH; s_r1 = -1; s_c0 = WW; s_c1 = -1; }
    __syncthreads();                                   // B1

    // ---- merge pass (event-masked dedup'd unions; R11 core) ----
    if (fgbits) {
        unsigned up = 0;
        if (row > 0) {
            const int wi  = col0 >> 5;
            const int off = col0 & 31;
            unsigned w0 = rowbits[row - 1][wi];
            unsigned w1 = (wi < 3) ? rowbits[row - 1][wi + 1] : 0u;
            unsigned long long uv = ((unsigned long long)w1 << 32) | w0;
            if (off == 16) {
                up = (unsigned)(uv >> 15) & 0x3FFFFu;
            } else {
                unsigned lw = (col0 > 0) ? rowbits[row - 1][wi - 1] : 0u;
                up = (unsigned)((uv << 1) | (lw >> 31)) & 0x3FFFFu;
            }
        }
        if ((fgbits & 1u) && leftbit) uni(L, base, base - 1);
        const unsigned ULv = up & 0xFFFFu;
        const unsigned UPv = (up >> 1) & 0xFFFFu;
        const unsigned URv = (up >> 2) & 0xFFFFu;
        const unsigned lFv = ((fgbits << 1) | leftbit) & 0xFFFFu;
        const unsigned rFv = (fgbits >> 1) | (rightbit << 15);
        unsigned m = fgbits & ( (~lFv & (ULv | UPv | URv))
                              | (lFv & ((UPv & ~ULv) | (~rFv & URv & ~UPv))) );
        while (m) {
            int k = __ffs(m) - 1; m &= m - 1;
            unsigned t = ~fgbits & ((1u << k) - 1u);
            int head = base + (t ? (32 - __builtin_clz(t)) : 0);
            unsigned UL = (ULv >> k) & 1u;
            unsigned UP = (UPv >> k) & 1u;
            unsigned UR = (URv >> k) & 1u;
            unsigned lF = (lFv >> k) & 1u;
            unsigned rF = (rFv >> k) & 1u;
            int i = base + k;
            if (!lF) {
                if (UL)        uni(L, head, i - WW - 1);
                if (UP && !UL) uni(L, head, i - WW);
                if (UR && !UP) uni(L, head, i - WW + 1);
            } else {
                if (UP && !UL)        uni(L, head, i - WW);
                if (!rF && UR && !UP) uni(L, head, i - WW + 1);
            }
        }
    }
    __syncthreads();                                   // B2

    // ---- flatten + areas, overlapped (no barrier between them) ----
    // Masked finds walk low-16 bits; area atomicAdds touch only true roots
    // (stable after B2); compression stores touch only non-roots. Disjoint.
    int rr[PPT];
    int firstRoot = 0x7FFFFFFF;
    {
        int cur = -1;
#pragma unroll
        for (int k = 0; k < PPT; ++k) {
            rr[k] = -1;
            if (fgbits & (1u << k)) {
                if (k == 0 || !(fgbits & (1u << (k - 1)))) {
                    cur = findRootM(L, base + k);
                    if (cur != base + k) L[base + k] = cur;   // compress non-roots only
                }
                rr[k] = cur;
                if (firstRoot == 0x7FFFFFFF) firstRoot = cur;
            }
        }
    }
    {
        const int R0 = wmini(firstRoot);
        int giant = 0, prev = -1, cnt = 0;
#pragma unroll
        for (int k = 0; k < PPT; ++k) {
            if (!(fgbits & (1u << k))) continue;
            int r = rr[k];
            if (r == R0) ++giant;
            else if (r == prev) ++cnt;
            else {
                if (cnt) atomicAdd(&L[prev], cnt << 16);
                prev = r; cnt = 1;
            }
        }
        if (cnt) atomicAdd(&L[prev], cnt << 16);
        int g = wsumi(giant);
        if (lane == 0 && R0 != 0x7FFFFFFF && g) atomicAdd(&L[R0], g << 16);
    }
    __syncthreads();                                   // B4

    // ---- top-2 scan over run heads (fg roots only) ----
    unsigned b1 = 0, b2 = 0;
    {
        unsigned m = fgbits & ~(fgbits << 1);          // chunk-local run heads
        while (m) {
            int k = __ffs(m) - 1; m &= m - 1;
            int h = base + k;
            int e = L[h];
            if ((e & 0xFFFF) == h && (e >> 16) != 0) {
                unsigned key = ((unsigned)(e >> 16) << 15) | (unsigned)(BIGL - h);
                if (key > b1) { b2 = b1; b1 = key; }
                else if (key > b2) b2 = key;
            }
        }
    }
    for (int o = 32; o; o >>= 1) {
        unsigned p1 = __shfl_xor(b1, o, 64);
        unsigned p2 = __shfl_xor(b2, o, 64);
        if (p1 > b1) { b2 = (b1 > p2 ? b1 : p2); b1 = p1; }
        else if (p1 > b2) b2 = p1;
    }
    if (lane == 0) { s_wk[wid * 2] = b1; s_wk[wid * 2 + 1] = b2; }
    __syncthreads();                                   // B5

    // ---- every thread: global top-2 (incl. background) from s_wk/s_wi ----
    unsigned g1 = 0, g2 = 0;
    {
        int fgtot = 0;
#pragma unroll
        for (int w = 0; w < 16; ++w) fgtot += s_wi[w];
        int bg = HWPX - fgtot;
        if (bg > 0) g1 = (unsigned)bg << 15;           // bg key (label BIGL -> suffix 0)
#pragma unroll
        for (int w = 0; w < 16; ++w) {
            unsigned o1 = s_wk[w * 2], o2 = s_wk[w * 2 + 1];
            if (o1 > g1) { g2 = (g1 > o2 ? g1 : o2); g1 = o1; }
            else if (o1 > g2) g2 = o1;
        }
    }
    const unsigned k2 = g2;
    const bool have2 = (k2 >> 15) != 0;
    const int j = BIGL - (int)(k2 & 0x7FFFu);          // runner-up (BIGL == bg)

    // ---- bbox of component j (wave-combined atomics) ----
    if (have2) {
        int lc0 = WW, lc1 = -1;
#pragma unroll
        for (int k = 0; k < PPT; ++k) {
            bool inc = (fgbits & (1u << k)) ? (rr[k] == j) : (j == BIGL);
            if (inc) {
                int c = col0 + k;
                lc0 = min(lc0, c); lc1 = max(lc1, c);
            }
        }
        int lr0 = (lc1 >= 0) ? row : HH;
        int lr1 = (lc1 >= 0) ? row : -1;
        lr0 = wmini(lr0); lr1 = wmaxi(lr1);
        lc0 = wmini(lc0); lc1 = wmaxi(lc1);
        if (lane == 0 && lr1 >= 0) {
            atomicMin(&s_r0, lr0); atomicMax(&s_r1, lr1);
            atomicMin(&s_c0, lc0); atomicMax(&s_c1, lc1);
        }
    }
    __syncthreads();                                   // B6

    // ---- sum inside box (from registers) ----
    float bsum = 0.f;
    if (have2) {
        int r0 = s_r0, r1 = s_r1, c0 = s_c0, c1 = s_c1;
        if (row >= r0 && row <= r1) {
#pragma unroll
            for (int k = 0; k < PPT; ++k) {
                int c = col0 + k;
                if (c >= c0 && c <= c1) bsum += vals[k];
            }
        }
    }
    bsum = wsumf(bsum);
    if (lane == 0) s_wB[wid] = bsum;
    __syncthreads();                                   // B7
    if (tid == 0) {
        float tot = 0.f, bx = 0.f;
#pragma unroll
        for (int w = 0; w < 16; ++w) { tot += s_wA[w]; bx += s_wB[w]; }
        losses[blockIdx.x] = (tot - bx) * (1.0f / 16384.0f);
    }
}

// lean tail: one wave, no LDS, no barrier
__global__ void reduce_kernel(const float* __restrict__ losses, float* __restrict__ out, int n) {
    int t = threadIdx.x;                      // 64 threads
    float v = 0.f;
    for (int i = t; i < n; i += 64) v += losses[i];
    for (int off = 32; off; off >>= 1) v += __shfl_down(v, off, 64);
    if (t == 0) out[0] = v / (float)n;
}

extern "C" void kernel_launch(void* const* d_in, const int* in_sizes, int n_in,
                              void* d_out, int out_size, void* d_ws, size_t ws_size,
                              hipStream_t stream) {
    const float* masks = (const float*)d_in[0];
    float* out = (float*)d_out;
    float* losses = (float*)d_ws;
    int nmask = in_sizes[0] / HWPX;          // 8*16 = 128
    cc_kernel<<<nmask, NT, 0, stream>>>(masks, losses);
    reduce_kernel<<<1, 64, 0, stream>>>(losses, out, nmask);
}